// Round 1
// baseline (2735.713 us; speedup 1.0000x reference)
//
#include <hip/hip_runtime.h>

typedef unsigned short u16;
typedef __bf16 bf16x8 __attribute__((ext_vector_type(8)));
typedef float f32x4 __attribute__((ext_vector_type(4)));

__device__ __forceinline__ u16 f2bf(float f) {
    unsigned u = __float_as_uint(f);
    u += 0x7FFFu + ((u >> 16) & 1u);
    return (u16)(u >> 16);
}
__device__ __forceinline__ float bf2f(u16 h) {
    return __uint_as_float(((unsigned)h) << 16);
}

__device__ __forceinline__ void gll16(const void* g, void* l) {
    __builtin_amdgcn_global_load_lds(
        (const __attribute__((address_space(1))) void*)g,
        (__attribute__((address_space(3))) void*)l, 16, 0, 0);
}

// ---------------------------------------------------------------------------
// NT GEMM: C[m][n] = sum_k A[m][k] * Bt[n][k], A [M][lda] bf16, Bt [N][ldb] bf16
// 128x128 tile, BK=32, 256 threads (4 waves in 2x2), MFMA 16x16x32 bf16.
// EPI: 0 = bf16 store; 1 = elu + bf16 store; 2 = f32 store; 3 = f32 + bf16 store
// ---------------------------------------------------------------------------
template<int EPI>
__global__ __launch_bounds__(256)
void gemm_nt(const u16* __restrict__ A, const u16* __restrict__ Bt,
             float* __restrict__ outF, u16* __restrict__ outH,
             int K, int lda, int ldb, int ldc, int ntn, int ntm)
{
    __shared__ __align__(16) u16 As[128 * 32];
    __shared__ __align__(16) u16 Bs[128 * 32];

    // XCD-aware bijective swizzle (nwg % 8 == 0 for all our launches)
    int nwg = ntn * ntm;
    int bid = (int)blockIdx.x;
    int cpx = nwg >> 3;
    bid = (bid & 7) * cpx + (bid >> 3);
    const int mt = bid / ntn, nt = bid - mt * ntn;
    const size_t m0 = (size_t)mt * 128, n0 = (size_t)nt * 128;

    const int t = threadIdx.x;
    const int lane = t & 63, w = t >> 6;
    const int fr = lane & 15, fq = lane >> 4;       // frag row sel, k-octet
    const int wr = (w >> 1) * 64, wc = (w & 1) * 64; // wave quadrant

    // staging: thread t loads 16B: row = t>>2 (+64 for 2nd issue), k-octet = t&3
    const int srow = t >> 2, skb = t & 3;
    const u16* ga0 = A  + (m0 + srow) * (size_t)lda + skb * 8;
    const u16* ga1 = ga0 + (size_t)64 * lda;
    const u16* gb0 = Bt + (n0 + srow) * (size_t)ldb + skb * 8;
    const u16* gb1 = gb0 + (size_t)64 * ldb;
    char* la0 = (char*)As + t * 16;
    char* la1 = la0 + 4096;
    char* lb0 = (char*)Bs + t * 16;
    char* lb1 = lb0 + 4096;

    f32x4 acc[4][4];
#pragma unroll
    for (int i = 0; i < 4; i++)
#pragma unroll
        for (int j = 0; j < 4; j++) {
            f32x4 z = {0.f, 0.f, 0.f, 0.f};
            acc[i][j] = z;
        }

    for (int kk = 0; kk < K; kk += 32) {
        __syncthreads();
        gll16(ga0 + kk, la0);
        gll16(ga1 + kk, la1);
        gll16(gb0 + kk, lb0);
        gll16(gb1 + kk, lb1);
        __syncthreads();

        bf16x8 af[4], bg[4];
#pragma unroll
        for (int i = 0; i < 4; i++)
            af[i] = *(const bf16x8*)&As[(wr + i * 16 + fr) * 32 + fq * 8];
#pragma unroll
        for (int i = 0; i < 4; i++)
            bg[i] = *(const bf16x8*)&Bs[(wc + i * 16 + fr) * 32 + fq * 8];
#pragma unroll
        for (int i = 0; i < 4; i++)
#pragma unroll
            for (int j = 0; j < 4; j++)
                acc[i][j] = __builtin_amdgcn_mfma_f32_16x16x32_bf16(
                    af[i], bg[j], acc[i][j], 0, 0, 0);
    }

    // epilogue: C/D layout (m89-verified): col = lane&15, row = (lane>>4)*4 + reg
#pragma unroll
    for (int i = 0; i < 4; i++) {
#pragma unroll
        for (int j = 0; j < 4; j++) {
            f32x4 v = acc[i][j];
            if (EPI == 1) {
#pragma unroll
                for (int r = 0; r < 4; r++)
                    v[r] = v[r] > 0.f ? v[r] : (expf(v[r]) - 1.f);
            }
            const size_t row = m0 + wr + i * 16 + fq * 4;
            const size_t col = n0 + wc + j * 16 + fr;
#pragma unroll
            for (int r = 0; r < 4; r++) {
                const size_t off = (row + r) * (size_t)ldc + col;
                if (EPI == 2 || EPI == 3) outF[off] = v[r];
                if (EPI == 0 || EPI == 1 || EPI == 3) outH[off] = f2bf(v[r]);
            }
        }
    }
}

// ---------------------------------------------------------------------------
// elementwise f32 -> bf16 (x), vectorized float4 -> ushort4
// ---------------------------------------------------------------------------
__global__ __launch_bounds__(256)
void cvt_bf16(const float* __restrict__ in, u16* __restrict__ out, int n4)
{
    int idx = blockIdx.x * 256 + threadIdx.x;
    if (idx >= n4) return;
    float4 v = ((const float4*)in)[idx];
    ushort4 o;
    o.x = f2bf(v.x); o.y = f2bf(v.y); o.z = f2bf(v.z); o.w = f2bf(v.w);
    ((ushort4*)out)[idx] = o;
}

// ---------------------------------------------------------------------------
// transpose + convert: in [R][C] f32 -> out [C][R] bf16 (32x32 LDS tiles)
// ---------------------------------------------------------------------------
__global__ __launch_bounds__(256)
void transpose_cvt(const float* __restrict__ in, u16* __restrict__ out, int R, int C)
{
    __shared__ u16 tile[32][36];
    const int t = threadIdx.x;
    const int r = t >> 3, c4 = (t & 7) * 4;
    const int gr = blockIdx.y * 32 + r;
    const int gc = blockIdx.x * 32 + c4;
    float4 v = *(const float4*)(in + (size_t)gr * C + gc);
    tile[r][c4 + 0] = f2bf(v.x);
    tile[r][c4 + 1] = f2bf(v.y);
    tile[r][c4 + 2] = f2bf(v.z);
    tile[r][c4 + 3] = f2bf(v.w);
    __syncthreads();
    const int orow = blockIdx.x * 32 + r;
    const int oc = blockIdx.y * 32 + c4;
    ushort4 o;
    o.x = tile[c4 + 0][r]; o.y = tile[c4 + 1][r];
    o.z = tile[c4 + 2][r]; o.w = tile[c4 + 3][r];
    *(ushort4*)(out + (size_t)orow * R + oc) = o;
}

// ---------------------------------------------------------------------------
// f1[i] = sum_h a[h]     * WhT[h][i]
// f2[i] = sum_h a[8192+h]* WhT[h][i]
// grid (4, 64): block = 2048 i's x 128 h's, atomicAdd partials
// ---------------------------------------------------------------------------
__global__ __launch_bounds__(256)
void f1f2_kernel(const u16* __restrict__ WhT, const float* __restrict__ a_gat,
                 float* __restrict__ f1, float* __restrict__ f2)
{
    const int t = threadIdx.x;
    const int i0 = blockIdx.x * 2048 + t * 8;
    const int h0 = blockIdx.y * 128;
    float s1[8] = {0, 0, 0, 0, 0, 0, 0, 0};
    float s2[8] = {0, 0, 0, 0, 0, 0, 0, 0};
    for (int hh = 0; hh < 128; ++hh) {
        const int h = h0 + hh;
        const float a1 = a_gat[h], a2 = a_gat[8192 + h];
        const u16* p = WhT + (size_t)h * 8192 + i0;
        ushort4 v0 = *(const ushort4*)p;
        ushort4 v1 = *(const ushort4*)(p + 4);
        float wv[8] = {bf2f(v0.x), bf2f(v0.y), bf2f(v0.z), bf2f(v0.w),
                       bf2f(v1.x), bf2f(v1.y), bf2f(v1.z), bf2f(v1.w)};
#pragma unroll
        for (int j = 0; j < 8; j++) { s1[j] += a1 * wv[j]; s2[j] += a2 * wv[j]; }
    }
#pragma unroll
    for (int j = 0; j < 8; j++) {
        atomicAdd(&f1[i0 + j], s1[j]);
        atomicAdd(&f2[i0 + j], s2[j]);
    }
}

// ---------------------------------------------------------------------------
// per-row masked softmax of rank-1 logits: att[i][k] bf16
// z = leaky(f1[i] + f2[k], 0.2) where adj[i][k] > 0 else -inf
// one block (256 thr) per row; 32 elems/thread held in registers
// ---------------------------------------------------------------------------
__global__ __launch_bounds__(256)
void att_kernel(const float* __restrict__ adj, const float* __restrict__ f1,
                const float* __restrict__ f2, u16* __restrict__ att)
{
    const int i = blockIdx.x;
    const int t = threadIdx.x;
    __shared__ float red[4];
    const float4* arow = (const float4*)(adj + (size_t)i * 8192);
    const float4* f2v = (const float4*)f2;
    const float fi = f1[i];
    float z[32];
    float lmax = -3.0e38f;
#pragma unroll
    for (int j = 0; j < 8; j++) {
        const int idx = t + j * 256;
        float4 a4 = arow[idx];
        float4 g4 = f2v[idx];
        float zz;
        zz = fi + g4.x; zz = zz > 0.f ? zz : 0.2f * zz; z[j * 4 + 0] = (a4.x > 0.f) ? zz : -3.0e38f;
        zz = fi + g4.y; zz = zz > 0.f ? zz : 0.2f * zz; z[j * 4 + 1] = (a4.y > 0.f) ? zz : -3.0e38f;
        zz = fi + g4.z; zz = zz > 0.f ? zz : 0.2f * zz; z[j * 4 + 2] = (a4.z > 0.f) ? zz : -3.0e38f;
        zz = fi + g4.w; zz = zz > 0.f ? zz : 0.2f * zz; z[j * 4 + 3] = (a4.w > 0.f) ? zz : -3.0e38f;
        lmax = fmaxf(lmax, fmaxf(fmaxf(z[j * 4 + 0], z[j * 4 + 1]),
                                 fmaxf(z[j * 4 + 2], z[j * 4 + 3])));
    }
#pragma unroll
    for (int off = 32; off; off >>= 1) lmax = fmaxf(lmax, __shfl_xor(lmax, off));
    if ((t & 63) == 0) red[t >> 6] = lmax;
    __syncthreads();
    lmax = fmaxf(fmaxf(red[0], red[1]), fmaxf(red[2], red[3]));

    float lsum = 0.f;
#pragma unroll
    for (int j = 0; j < 32; j++) {
        float p = (z[j] > -1.0e38f) ? exp2f((z[j] - lmax) * 1.44269504089f) : 0.f;
        z[j] = p;
        lsum += p;
    }
#pragma unroll
    for (int off = 32; off; off >>= 1) lsum += __shfl_xor(lsum, off);
    __syncthreads();               // guard red reuse
    if ((t & 63) == 0) red[t >> 6] = lsum;
    __syncthreads();
    lsum = red[0] + red[1] + red[2] + red[3];
    const float inv = 1.0f / lsum;

    u16* orow = att + (size_t)i * 8192;
#pragma unroll
    for (int j = 0; j < 8; j++) {
        const int idx = t + j * 256;
        ushort4 o;
        o.x = f2bf(z[j * 4 + 0] * inv);
        o.y = f2bf(z[j * 4 + 1] * inv);
        o.z = f2bf(z[j * 4 + 2] * inv);
        o.w = f2bf(z[j * 4 + 3] * inv);
        *(ushort4*)(orow + idx * 4) = o;
    }
}

// ---------------------------------------------------------------------------
extern "C" void kernel_launch(void* const* d_in, const int* in_sizes, int n_in,
                              void* d_out, int out_size, void* d_ws, size_t ws_size,
                              hipStream_t stream)
{
    const float* x     = (const float*)d_in[0];
    const float* adj   = (const float*)d_in[1];
    const float* W_gat = (const float*)d_in[3];
    const float* a_gat = (const float*)d_in[4];
    const float* W_gc2 = (const float*)d_in[5];
    const float* W_gc3 = (const float*)d_in[6];

    char* ws = (char*)d_ws;
    u16*   WhT   = (u16*)(ws);                    // 8192x8192 bf16   134217728 B
    u16*   x_bf  = (u16*)(ws + 134217728);        // 8192x512        8388608 B
    u16*   WgT   = (u16*)(ws + 142606336);        // 8192x512        8388608 B
    u16*   xw2T  = (u16*)(ws + 150994944);        // 256x8192        4194304 B
    u16*   xw3T  = (u16*)(ws + 155189248);        // 256x8192        4194304 B
    u16*   W2T   = (u16*)(ws + 159383552);        // 256x512         262144 B
    u16*   W3T   = (u16*)(ws + 159645696);        // 256x512         262144 B
    u16*   mu_bf = (u16*)(ws + 159907840);        // 8192x256        4194304 B
    float* f1    = (float*)(ws + 164102144);      // 8192 f32        32768 B
    float* f2    = (float*)(ws + 164134912);      // 8192 f32        32768 B

    char* outc = (char*)d_out;
    u16*   att     = (u16*)outc;                  // scratch in adj_rec region
    u16*   hidden  = (u16*)(outc + 134217728);    // scratch in adj_rec region
    float* adj_rec = (float*)d_out;
    float* muF     = (float*)(outc + 268435456);
    float* lvF     = (float*)(outc + 268435456 + 8388608);

    // 1) dtype conversions / transposes
    cvt_bf16<<<4096, 256, 0, stream>>>(x, x_bf, 1048576);
    transpose_cvt<<<dim3(256, 16), 256, 0, stream>>>(W_gat, WgT, 512, 8192);
    transpose_cvt<<<dim3(8, 16), 256, 0, stream>>>(W_gc2, W2T, 512, 256);
    transpose_cvt<<<dim3(8, 16), 256, 0, stream>>>(W_gc3, W3T, 512, 256);

    // 2) WhT[h][i] = sum_f W_gat[f][h] * x[i][f]   (Wh transposed)
    gemm_nt<0><<<4096, 256, 0, stream>>>(WgT, x_bf, (float*)nullptr, WhT,
                                         512, 512, 512, 8192, 64, 64);

    // 3) attention logit vectors f1, f2
    hipMemsetAsync(f1, 0, 65536, stream);
    f1f2_kernel<<<dim3(4, 64), 256, 0, stream>>>(WhT, a_gat, f1, f2);

    // 4) masked row softmax -> att bf16
    att_kernel<<<8192, 256, 0, stream>>>(adj, f1, f2, att);

    // 5) hidden1 = elu(att @ Wh)   [8192 x 8192]
    gemm_nt<1><<<4096, 256, 0, stream>>>(att, WhT, (float*)nullptr, hidden,
                                         8192, 8192, 8192, 8192, 64, 64);

    // 6) xw2T[c][k] = (x @ W_gc2)^T, xw3T likewise
    gemm_nt<0><<<128, 256, 0, stream>>>(W2T, x_bf, (float*)nullptr, xw2T,
                                        512, 512, 512, 8192, 64, 2);
    gemm_nt<0><<<128, 256, 0, stream>>>(W3T, x_bf, (float*)nullptr, xw3T,
                                        512, 512, 512, 8192, 64, 2);

    // 7) mu = hidden1 @ xw2 (f32 out + bf16 copy), logvar = hidden1 @ xw3
    gemm_nt<3><<<128, 256, 0, stream>>>(hidden, xw2T, muF, mu_bf,
                                        8192, 8192, 8192, 256, 2, 64);
    gemm_nt<2><<<128, 256, 0, stream>>>(hidden, xw3T, lvF, (u16*)nullptr,
                                        8192, 8192, 8192, 256, 2, 64);

    // 8) adj_rec = mu @ mu^T  (overwrites att/hidden scratch)
    gemm_nt<2><<<4096, 256, 0, stream>>>(mu_bf, mu_bf, adj_rec, (u16*)nullptr,
                                         256, 256, 256, 8192, 64, 64);
}